// Round 3
// baseline (1475.350 us; speedup 1.0000x reference)
//
#include <hip/hip_runtime.h>
#include <stdint.h>

#define NPIX 1024
#define NEDGE 1984
#define NSORT 2048
#define CHUNK 16
#define CNTW (NPIX + 2)   // pad rows: stride 2052B -> replay lanes hit distinct banks

struct SMem {
  union {
    unsigned long long keys[NSORT];   // 16384 B  (sort + phase1)
    uint16_t cnt[CHUNK][CNTW];        // 32832 B  (phase2 replay)
    double   red[256];                // 2048 B   (final reduction)
  } u;
  float    Pw[NPIX];          // window y_pred
  uint16_t lab[NPIX];         // CC labels (min pixel id + 1), 0 = unlabeled
  uint16_t par[NPIX];         // union-find parent
  uint32_t tot[NPIX];         // labeled-node count per root (u32 for LDS atomicAdd)
  uint16_t labDense[NPIX];    // dense label id, stored at component-min pixel
  uint16_t recE[NPIX];        // merge records (<= ~1023 used)
  uint16_t recA[NPIX];
  uint16_t recB[NPIX];
  uint32_t totprod[NPIX];     // totA*totB at merge time
  uint32_t same[NPIX];        // same-label pairs at merge (filled by replay)
  uint8_t  maskv[NPIX];       // T==0 (background / labeled)
  uint8_t  gtclass[NEDGE];    // # endpoints with T!=0 : 0,1,2
  unsigned int minPb, maxPb, minTb, maxTb, Ssum;
  int nlabs, Msh, changed;
};

__device__ __forceinline__ void edge_nodes(int e, int& a, int& b) {
  if (e < 992) { int r = e / 31; int c = e - r * 31; a = (r << 5) + c; b = a + 1; }
  else         { a = e - 992; b = a + 32; }
}

// path-halving find against batch-start forest; concurrent halving writes are
// ancestor-safe because unions are deferred to the wave-serial phase.
__device__ __forceinline__ int findh(volatile uint16_t* par, int x) {
  int p = par[x];
  while (p != x) {
    int gp = par[p];
    par[x] = (uint16_t)gp;
    x = gp; p = par[x];
  }
  return x;
}

__global__ __launch_bounds__(256) void malis_kernel(
    const float* __restrict__ y_true, const float* __restrict__ y_pred,
    double* __restrict__ part_out)
{
  __shared__ SMem s;
  const int tid  = threadIdx.x;
  const int bid  = blockIdx.x;
  const int sign = bid & 1;          // 0 = neg, 1 = pos
  const int win  = (bid >> 1) & 63;
  const int bat  = bid >> 7;
  const int wr = win >> 3, wc = win & 7;

  if (tid == 0) {
    s.minPb = 0xFFFFFFFFu; s.maxPb = 0u; s.minTb = 0xFFFFFFFFu; s.maxTb = 0u;
    s.nlabs = 0; s.Msh = 0; s.Ssum = 0u;
  }
  __syncthreads();

  // ---- load window; min/max over BOTH batches for the exact skip predicate
  for (int i = tid; i < 2 * NPIX; i += 256) {
    int bb = i >> 10, p = i & (NPIX - 1);
    int r = p >> 5, c = p & 31;
    size_t g = ((size_t)(bb * 256 + wr * 32 + r)) * 256 + (size_t)(wc * 32 + c);
    float pv = y_pred[g], tv = y_true[g];
    atomicMin(&s.minPb, __float_as_uint(pv));   // valid: all values >= 0
    atomicMax(&s.maxPb, __float_as_uint(pv));
    atomicMin(&s.minTb, __float_as_uint(tv));
    atomicMax(&s.maxTb, __float_as_uint(tv));
    if (bb == bat) { s.Pw[p] = pv; s.maskv[p] = (tv == 0.0f) ? 1 : 0; }
  }
  __syncthreads();

  {
    float mnP = __uint_as_float(s.minPb), mxP = __uint_as_float(s.maxPb);
    float mnT = __uint_as_float(s.minTb), mxT = __uint_as_float(s.maxTb);
    if (mnP == 1.0f || mxP == 0.0f || mnT == 1.0f || mxT == 0.0f) {
      if (tid == 0) part_out[bid] = 0.0;
      return;                                   // uniform across block
    }
  }

  // ---- edge keys (cost desc, index asc  ->  pack (~bits(cost), e), sort asc)
  for (int e = tid; e < NSORT; e += 256) {
    if (e < NEDGE) {
      int a, b; edge_nodes(e, a, b);
      int cls = (s.maskv[a] ? 0 : 1) + (s.maskv[b] ? 0 : 1);
      s.gtclass[e] = (uint8_t)cls;
      float cost = s.Pw[a] + s.Pw[b];
      if (sign == 0) { if (cls == 2) cost = 20.0f; }   // costs_n[gt>20]=20
      else           { if (cls == 0) cost = 0.0f;  }   // costs_p[gt<10]=0
      s.u.keys[e] = (((unsigned long long)(__float_as_uint(cost) ^ 0xFFFFFFFFu)) << 32)
                    | (unsigned long long)(unsigned)e;
    } else {
      s.u.keys[e] = ~0ull;                             // pad sorts to end
    }
  }
  for (int p = tid; p < NPIX; p += 256) {
    s.lab[p] = s.maskv[p] ? (uint16_t)(p + 1) : (uint16_t)0;
    s.par[p] = (uint16_t)p;
    s.tot[p] = (uint32_t)s.maskv[p];
    s.same[p] = 0u;
    s.totprod[p] = 0u;
  }
  __syncthreads();

  // ---- 8-connected components of maskv: monotone min-propagation + jumps
  for (;;) {
    if (tid == 0) s.changed = 0;
    __syncthreads();
    for (int p = tid; p < NPIX; p += 256) {
      if (!s.maskv[p]) continue;
      int r = p >> 5, c = p & 31;
      unsigned m = s.lab[p];
      bool up = r > 0, dn = r < 31, lf = c > 0, rt = c < 31;
      if (up) {
        if (s.maskv[p-32])       { unsigned v = s.lab[p-32]; if (v < m) m = v; }
        if (lf && s.maskv[p-33]) { unsigned v = s.lab[p-33]; if (v < m) m = v; }
        if (rt && s.maskv[p-31]) { unsigned v = s.lab[p-31]; if (v < m) m = v; }
      }
      if (dn) {
        if (s.maskv[p+32])       { unsigned v = s.lab[p+32]; if (v < m) m = v; }
        if (lf && s.maskv[p+31]) { unsigned v = s.lab[p+31]; if (v < m) m = v; }
        if (rt && s.maskv[p+33]) { unsigned v = s.lab[p+33]; if (v < m) m = v; }
      }
      if (lf && s.maskv[p-1]) { unsigned v = s.lab[p-1]; if (v < m) m = v; }
      if (rt && s.maskv[p+1]) { unsigned v = s.lab[p+1]; if (v < m) m = v; }
      unsigned m2 = s.lab[m - 1]; if (m2 && m2 < m) m = m2;   // pointer jump
      m2 = s.lab[m - 1];          if (m2 && m2 < m) m = m2;   // jump again
      if (m < (unsigned)s.lab[p]) { s.lab[p] = (uint16_t)m; s.changed = 1; }
    }
    __syncthreads();
    int ch = s.changed;
    __syncthreads();
    if (!ch) break;
  }

  // ---- compact labels to dense ids (assignment order irrelevant: sums exact)
  for (int p = tid; p < NPIX; p += 256)
    if (s.maskv[p] && s.lab[p] == (uint16_t)(p + 1))
      s.labDense[p] = (uint16_t)atomicAdd(&s.nlabs, 1);
  __syncthreads();

  // ---- bitonic sort (ascending) of 2048 keys, 256 threads
  for (int k = 2; k <= NSORT; k <<= 1) {
    for (int j = k >> 1; j > 0; j >>= 1) {
      __syncthreads();
      for (int i = tid; i < NSORT; i += 256) {
        int ixj = i ^ j;
        if (ixj > i) {
          unsigned long long A = s.u.keys[i], B = s.u.keys[ixj];
          bool asc = ((i & k) == 0);
          if ((A > B) == asc) { s.u.keys[i] = B; s.u.keys[ixj] = A; }
        }
      }
    }
  }
  __syncthreads();

  // ---- phase 1: wave-cooperative speculative batch Kruskal (wave 0 only).
  // Batches of 64 sorted edges: parallel speculative finds (unions deferred ->
  // concurrent path-halving is safe), then lockstep in-register resolution of
  // intra-batch merges via ballot/shfl. Merge slot j lives in lane j's regs.
  // NOTE: all __shfl/__ballot calls MUST be in uniform control flow — on CDNA
  // ds_bpermute reads 0 from EXEC-masked-off source lanes.
  if (tid < 64) {
    const int lane = tid;
    volatile uint16_t* vpar = (volatile uint16_t*)s.par;
    volatile uint32_t* vtot = (volatile uint32_t*)s.tot;
    int mTotal = 0;                       // emitted record count (uniform)
    for (int base = 0; base < NSORT; base += 64) {
      // step A: speculative find + size read (batch-start state)
      unsigned long long key = s.u.keys[base + lane];
      unsigned e = (unsigned)key;
      int ra = 0, rb = 0; unsigned sa = 0, sb = 0;
      int valid = (e < (unsigned)NEDGE) ? 1 : 0;
      if (!__ballot(valid)) continue;          // all-padding batch (uniform)
      if (valid) {
        int a, b; edge_nodes((int)e, a, b);
        ra = findh(vpar, a);
        rb = findh(vpar, b);
        sa = vtot[ra]; sb = vtot[rb];
      }
      // step B: lockstep serial resolution, state in registers
      int mb = 0;            // merges this batch
      int mFrom = -1, mTo = -1; unsigned szTo = 0;   // my merge slot
      for (int i = 0; i < 64; ++i) {
        if (!__shfl(valid, i, 64)) continue;
        int rA = __shfl(ra, i, 64);
        int rB = __shfl(rb, i, 64);
        unsigned sA = (unsigned)__shfl((int)sa, i, 64);
        unsigned sB = (unsigned)__shfl((int)sb, i, 64);
        unsigned eI = (unsigned)__shfl((int)e, i, 64);   // uniform exec: ALL lanes
        unsigned long long act = (mb == 0) ? 0ull
                                : (mb >= 64 ? ~0ull : ((1ull << mb) - 1ull));
        // chase roots through intra-batch merges ('from' values are unique)
        for (;;) {
          unsigned long long mm = __ballot(mFrom == rA) & act;
          if (!mm) break;
          rA = __shfl(mTo, __ffsll((long long)mm) - 1, 64);
        }
        for (;;) {
          unsigned long long mm = __ballot(mFrom == rB) & act;
          if (!mm) break;
          rB = __shfl(mTo, __ffsll((long long)mm) - 1, 64);
        }
        if (rA == rB) continue;
        // current sizes: latest intra-batch merge into rX wins, else start size
        unsigned long long ma = __ballot(mTo == rA) & act;
        if (ma) sA = (unsigned)__shfl((int)szTo, 63 - __clzll((long long)ma), 64);
        unsigned long long mbm = __ballot(mTo == rB) & act;
        if (mbm) sB = (unsigned)__shfl((int)szTo, 63 - __clzll((long long)mbm), 64);
        // record merge in slot mb (kept in lane mb's registers)
        if (lane == mb) { mFrom = rB; mTo = rA; szTo = sA + sB; }
        ++mb;
        // fire-and-forget LDS updates (no dependent reads on critical path)
        if (lane == 0) {
          s.par[rB] = (uint16_t)rA;                  // reference orientation
          atomicAdd(&s.tot[rA], sB);
          if (sB > 0) {
            s.recE[mTotal] = (uint16_t)eI;
            s.recA[mTotal] = (uint16_t)rA;
            s.recB[mTotal] = (uint16_t)rB;
            s.totprod[mTotal] = sA * sB;
          }
        }
        if (sB > 0) ++mTotal;                        // uniform
      }
    }
    if (lane == 0) s.Msh = mTotal;
  }
  __syncthreads();

  const int M = s.Msh;
  const int nlab = s.nlabs;

  // ---- phase 2: replay merge list per label (CHUNK labels at a time)
  for (int chb = 0; chb < nlab; chb += CHUNK) {
    for (int i = tid; i < (CHUNK * CNTW) / 2; i += 256) ((uint32_t*)s.u.cnt)[i] = 0u;
    __syncthreads();
    for (int p = tid; p < NPIX; p += 256) {
      if (s.maskv[p]) {
        int dl = (int)s.labDense[s.lab[p] - 1] - chb;
        if (dl >= 0 && dl < CHUNK) s.u.cnt[dl][p] = 1;
      }
    }
    __syncthreads();
    if (tid < CHUNK && M > 0) {
      int rbN = s.recB[0], raN = s.recA[0];
      for (int m = 0; m < M; ++m) {
        int rb = rbN, ra2 = raN;
        if (m + 1 < M) { rbN = s.recB[m + 1]; raN = s.recA[m + 1]; }  // prefetch
        unsigned cb = s.u.cnt[tid][rb];
        if (cb) {
          unsigned ca = s.u.cnt[tid][ra2];
          if (ca) atomicAdd(&s.same[m], ca * cb);   // integer, order-independent
          s.u.cnt[tid][ra2] = (uint16_t)(ca + cb);
        }
      }
    }
    __syncthreads();
  }

  // ---- normalization sum S (over ALL edges, pre-mask) and masked contribution
  unsigned mys = 0u;
  for (int m = tid; m < M; m += 256)
    mys += sign ? s.same[m] : (s.totprod[m] - s.same[m]);
  atomicAdd(&s.Ssum, mys);
  __syncthreads();
  const unsigned S = s.Ssum;

  double part = 0.0;
  if (S > 0u) {
    for (int m = tid; m < M; m += 256) {
      unsigned np = sign ? s.same[m] : (s.totprod[m] - s.same[m]);
      if (np == 0u) continue;
      int e = s.recE[m];
      int cls = s.gtclass[e];
      bool keep = sign ? (cls != 0)    // ewp[gt<20]=0  -> keep cls 1,2
                       : (cls == 0);   // ewn[gt>=10]=0 -> keep cls 0
      if (!keep) continue;
      int a, b; edge_nodes(e, a, b);
      double fa, fb;
      if (sign) {
        double da = 20.0 - (double)s.Pw[a], db = 20.0 - (double)s.Pw[b];
        fa = da * da; fb = db * db;
      } else {
        fa = (double)s.Pw[a] * (double)s.Pw[a];
        fb = (double)s.Pw[b] * (double)s.Pw[b];
      }
      part += (double)np * (fa + fb);
    }
  }
  __syncthreads();           // cnt/keys region dead; reuse as red[]
  s.u.red[tid] = part;
  __syncthreads();
  for (int st = 128; st > 0; st >>= 1) {
    if (tid < st) s.u.red[tid] += s.u.red[tid + st];
    __syncthreads();
  }
  if (tid == 0) part_out[bid] = (S > 0u) ? (s.u.red[0] / (double)S) : 0.0;
}

__global__ __launch_bounds__(256) void final_reduce(
    const double* __restrict__ part, float* __restrict__ out)
{
  __shared__ double r[256];
  int t = threadIdx.x;
  r[t] = part[t];
  __syncthreads();
  for (int st = 128; st > 0; st >>= 1) {
    if (t < st) r[t] += r[t + st];
    __syncthreads();
  }
  if (t == 0) out[0] = (float)r[0];
}

extern "C" void kernel_launch(void* const* d_in, const int* in_sizes, int n_in,
                              void* d_out, int out_size, void* d_ws, size_t ws_size,
                              hipStream_t stream) {
  const float* y_true = (const float*)d_in[0];
  const float* y_pred = (const float*)d_in[1];
  double* wsd = (double*)d_ws;            // 256 doubles of scratch
  malis_kernel<<<256, 256, 0, stream>>>(y_true, y_pred, wsd);
  final_reduce<<<1, 256, 0, stream>>>(wsd, (float*)d_out);
}

// Round 4
// 761.840 us; speedup vs baseline: 1.9366x; 1.9366x over previous
//
#include <hip/hip_runtime.h>
#include <stdint.h>

#define NPIX 1024
#define NEDGE 1984
#define NSORT 2048
#define CHUNK 16
#define CNTW (NPIX + 2)   // pad rows: stride 2052B -> replay lanes hit distinct banks

struct SMem {
  union {
    unsigned long long keys[NSORT];   // 16384 B  (sort + phase1)
    uint16_t cnt[CHUNK][CNTW];        // 32832 B  (phase2 replay)
    double   red[256];                // 2048 B   (final reduction)
  } u;
  float    Pw[NPIX];          // window y_pred
  uint16_t lab[NPIX];         // CC labels (min pixel id + 1), 0 = unlabeled
  uint16_t par[NPIX];         // union-find parent
  uint32_t tot[NPIX];         // labeled-node count per root
  uint16_t labDense[NPIX];    // dense label id, stored at component-min pixel
  uint16_t recE[NPIX];        // merge records (<= 1023 used)
  uint16_t recA[NPIX];
  uint16_t recB[NPIX];
  uint32_t totprod[NPIX];     // totA*totB at merge time
  uint32_t same[NPIX];        // same-label pairs at merge (filled by replay)
  uint8_t  maskv[NPIX];       // T==0 (background / labeled)
  uint8_t  gtclass[NEDGE];    // # endpoints with T!=0 : 0,1,2
  unsigned int minPb, maxPb, minTb, maxTb, Ssum;
  int nlabs, Msh, changed;
};

__device__ __forceinline__ void edge_nodes(int e, int& a, int& b) {
  if (e < 992) { int r = e / 31; int c = e - r * 31; a = (r << 5) + c; b = a + 1; }
  else         { a = e - 992; b = a + 32; }
}

__global__ __launch_bounds__(256) void malis_kernel(
    const float* __restrict__ y_true, const float* __restrict__ y_pred,
    double* __restrict__ part_out)
{
  __shared__ SMem s;
  const int tid  = threadIdx.x;
  const int bid  = blockIdx.x;
  const int sign = bid & 1;          // 0 = neg, 1 = pos
  const int win  = (bid >> 1) & 63;
  const int bat  = bid >> 7;
  const int wr = win >> 3, wc = win & 7;

  if (tid == 0) {
    s.minPb = 0xFFFFFFFFu; s.maxPb = 0u; s.minTb = 0xFFFFFFFFu; s.maxTb = 0u;
    s.nlabs = 0; s.Msh = 0; s.Ssum = 0u;
  }
  __syncthreads();

  // ---- load window; min/max over BOTH batches for the exact skip predicate.
  // Register pre-reduction first, then one atomic per var per thread.
  {
    unsigned mnP = 0xFFFFFFFFu, mxP = 0u, mnT = 0xFFFFFFFFu, mxT = 0u;
    for (int i = tid; i < 2 * NPIX; i += 256) {
      int bb = i >> 10, p = i & (NPIX - 1);
      int r = p >> 5, c = p & 31;
      size_t g = ((size_t)(bb * 256 + wr * 32 + r)) * 256 + (size_t)(wc * 32 + c);
      float pv = y_pred[g], tv = y_true[g];
      unsigned pu = __float_as_uint(pv), tu = __float_as_uint(tv);
      mnP = min(mnP, pu); mxP = max(mxP, pu);
      mnT = min(mnT, tu); mxT = max(mxT, tu);
      if (bb == bat) { s.Pw[p] = pv; s.maskv[p] = (tv == 0.0f) ? 1 : 0; }
    }
    atomicMin(&s.minPb, mnP); atomicMax(&s.maxPb, mxP);   // valid: values >= 0
    atomicMin(&s.minTb, mnT); atomicMax(&s.maxTb, mxT);
  }
  __syncthreads();

  {
    float mnP = __uint_as_float(s.minPb), mxP = __uint_as_float(s.maxPb);
    float mnT = __uint_as_float(s.minTb), mxT = __uint_as_float(s.maxTb);
    if (mnP == 1.0f || mxP == 0.0f || mnT == 1.0f || mxT == 0.0f) {
      if (tid == 0) part_out[bid] = 0.0;
      return;                                   // uniform across block
    }
  }

  // ---- edge keys (cost desc, index asc  ->  pack (~bits(cost), e), sort asc)
  for (int e = tid; e < NSORT; e += 256) {
    if (e < NEDGE) {
      int a, b; edge_nodes(e, a, b);
      int cls = (s.maskv[a] ? 0 : 1) + (s.maskv[b] ? 0 : 1);
      s.gtclass[e] = (uint8_t)cls;
      float cost = s.Pw[a] + s.Pw[b];
      if (sign == 0) { if (cls == 2) cost = 20.0f; }   // costs_n[gt>20]=20
      else           { if (cls == 0) cost = 0.0f;  }   // costs_p[gt<10]=0
      s.u.keys[e] = (((unsigned long long)(__float_as_uint(cost) ^ 0xFFFFFFFFu)) << 32)
                    | (unsigned long long)(unsigned)e;
    } else {
      s.u.keys[e] = ~0ull;                             // pad sorts to end
    }
  }
  for (int p = tid; p < NPIX; p += 256) {
    s.lab[p] = s.maskv[p] ? (uint16_t)(p + 1) : (uint16_t)0;
    s.par[p] = (uint16_t)p;
    s.tot[p] = (uint32_t)s.maskv[p];
    s.same[p] = 0u;
    s.totprod[p] = 0u;
  }
  __syncthreads();

  // ---- 8-connected components of maskv: monotone min-propagation + jumps
  for (;;) {
    if (tid == 0) s.changed = 0;
    __syncthreads();
    for (int p = tid; p < NPIX; p += 256) {
      if (!s.maskv[p]) continue;
      int r = p >> 5, c = p & 31;
      unsigned m = s.lab[p];
      bool up = r > 0, dn = r < 31, lf = c > 0, rt = c < 31;
      if (up) {
        if (s.maskv[p-32])       { unsigned v = s.lab[p-32]; if (v < m) m = v; }
        if (lf && s.maskv[p-33]) { unsigned v = s.lab[p-33]; if (v < m) m = v; }
        if (rt && s.maskv[p-31]) { unsigned v = s.lab[p-31]; if (v < m) m = v; }
      }
      if (dn) {
        if (s.maskv[p+32])       { unsigned v = s.lab[p+32]; if (v < m) m = v; }
        if (lf && s.maskv[p+31]) { unsigned v = s.lab[p+31]; if (v < m) m = v; }
        if (rt && s.maskv[p+33]) { unsigned v = s.lab[p+33]; if (v < m) m = v; }
      }
      if (lf && s.maskv[p-1]) { unsigned v = s.lab[p-1]; if (v < m) m = v; }
      if (rt && s.maskv[p+1]) { unsigned v = s.lab[p+1]; if (v < m) m = v; }
      unsigned m2 = s.lab[m - 1]; if (m2 && m2 < m) m = m2;   // pointer jump
      m2 = s.lab[m - 1];          if (m2 && m2 < m) m = m2;   // jump again
      if (m < (unsigned)s.lab[p]) { s.lab[p] = (uint16_t)m; s.changed = 1; }
    }
    __syncthreads();
    int ch = s.changed;
    __syncthreads();
    if (!ch) break;
  }

  // ---- compact labels to dense ids (assignment order irrelevant: sums exact)
  for (int p = tid; p < NPIX; p += 256)
    if (s.maskv[p] && s.lab[p] == (uint16_t)(p + 1))
      s.labDense[p] = (uint16_t)atomicAdd(&s.nlabs, 1);
  __syncthreads();

  // ---- bitonic sort (ascending) of 2048 keys, 256 threads
  for (int k = 2; k <= NSORT; k <<= 1) {
    for (int j = k >> 1; j > 0; j >>= 1) {
      __syncthreads();
      for (int i = tid; i < NSORT; i += 256) {
        int ixj = i ^ j;
        if (ixj > i) {
          unsigned long long A = s.u.keys[i], B = s.u.keys[ixj];
          bool asc = ((i & k) == 0);
          if ((A > B) == asc) { s.u.keys[i] = B; s.u.keys[ixj] = A; }
        }
      }
    }
  }
  __syncthreads();

  // ---- phase 1: wave-cooperative batch Kruskal (wave 0 only).
  // Per 64-edge batch: read-only speculative root walks (broadcast-friendly,
  // no same-address stores), candidate ballot (ra!=rb at batch start; non-
  // candidates provably never merge), then serial resolution over candidate
  // bits only, all cross-lane reads via v_readlane (uniform idx, no LDS).
  // All ballots/readlanes are in uniform control flow (CDNA exec-mask rule).
  if (tid < 64) {
    const int lane = tid;
    int mTotal = 0;                       // emitted record count (uniform)
    for (int base = 0; base < NSORT; base += 64) {
      // step A: speculative read-only finds against batch-start forest
      unsigned long long key = s.u.keys[base + lane];
      unsigned e = (unsigned)key;
      int ra = 0, rb = 0; unsigned sa = 0, sb = 0;
      bool valid = (e < (unsigned)NEDGE);
      if (valid) {
        int a, b; edge_nodes((int)e, a, b);
        int xa = a, xb = b;
        for (;;) {
          int pa = s.par[xa], pb = s.par[xb];   // dual walk: overlap latency
          if (pa == xa && pb == xb) break;
          xa = pa; xb = pb;                     // roots self-loop: safe
        }
        ra = xa; rb = xb;
        sa = s.tot[ra]; sb = s.tot[rb];
      }
      bool cand = valid && (ra != rb);
      unsigned long long cm = __ballot(cand);
      // pack: w0 = ra(10) | rb(10) | e(11);  w1 = sa(11) | sb(11)
      unsigned w0 = (unsigned)ra | ((unsigned)rb << 10) | (e << 20);
      unsigned w1 = sa | (sb << 11);

      // step B: serial resolution over candidate lanes only
      int mb = 0;                                  // merges this batch
      int mFrom = -1, mTo = -1; unsigned szTo = 0; // my merge slot (registers)
      while (cm) {
        int i = __ffsll((long long)cm) - 1;
        cm &= cm - 1;
        unsigned W0 = (unsigned)__builtin_amdgcn_readlane((int)w0, i);
        unsigned W1 = (unsigned)__builtin_amdgcn_readlane((int)w1, i);
        int rA = (int)(W0 & 1023u);
        int rB = (int)((W0 >> 10) & 1023u);
        unsigned eI = W0 >> 20;
        unsigned sA = W1 & 2047u;
        unsigned sB = W1 >> 11;
        unsigned long long act = (mb == 0) ? 0ull
                                : (mb >= 64 ? ~0ull : ((1ull << mb) - 1ull));
        // chase roots through intra-batch merges ('from' values are unique)
        for (;;) {
          unsigned long long mm = __ballot(mFrom == rA) & act;
          if (!mm) break;
          rA = __builtin_amdgcn_readlane(mTo, __ffsll((long long)mm) - 1);
        }
        for (;;) {
          unsigned long long mm = __ballot(mFrom == rB) & act;
          if (!mm) break;
          rB = __builtin_amdgcn_readlane(mTo, __ffsll((long long)mm) - 1);
        }
        if (rA == rB) continue;
        // current sizes: latest intra-batch merge into rX wins, else start size
        unsigned long long ma = __ballot(mTo == rA) & act;
        if (ma) sA = (unsigned)__builtin_amdgcn_readlane((int)szTo, 63 - __clzll((long long)ma));
        unsigned long long mbm = __ballot(mTo == rB) & act;
        if (mbm) sB = (unsigned)__builtin_amdgcn_readlane((int)szTo, 63 - __clzll((long long)mbm));
        // record merge in slot mb (kept in lane mb's registers)
        if (lane == mb) { mFrom = rB; mTo = rA; szTo = sA + sB; }
        ++mb;
        // fire-and-forget LDS updates (no dependent reads on critical path;
        // ds_add without return -> no waitcnt stall)
        if (lane == 0) {
          s.par[rB] = (uint16_t)rA;                  // reference orientation
          atomicAdd(&s.tot[rA], sB);
          if (sB > 0) {
            s.recE[mTotal] = (uint16_t)eI;
            s.recA[mTotal] = (uint16_t)rA;
            s.recB[mTotal] = (uint16_t)rB;
            s.totprod[mTotal] = sA * sB;
          }
        }
        if (sB > 0) ++mTotal;                        // uniform
      }

      // batched pointer-jump compression: 2 passes, pipelined (load-all /
      // gather-all / store-all), one write per distinct node -> conflict-free.
      if (mb && (base + 64 < NSORT)) {
        for (int pass = 0; pass < 2; ++pass) {
          uint16_t vv[16];
          #pragma unroll
          for (int j = 0; j < 16; ++j) vv[j] = s.par[j * 64 + lane];
          #pragma unroll
          for (int j = 0; j < 16; ++j) vv[j] = s.par[vv[j]];
          #pragma unroll
          for (int j = 0; j < 16; ++j) s.par[j * 64 + lane] = vv[j];
        }
      }
    }
    if (lane == 0) s.Msh = mTotal;
  }
  __syncthreads();

  const int M = s.Msh;
  const int nlab = s.nlabs;

  // ---- phase 2: replay merge list per label (CHUNK labels at a time)
  for (int chb = 0; chb < nlab; chb += CHUNK) {
    for (int i = tid; i < (CHUNK * CNTW) / 2; i += 256) ((uint32_t*)s.u.cnt)[i] = 0u;
    __syncthreads();
    for (int p = tid; p < NPIX; p += 256) {
      if (s.maskv[p]) {
        int dl = (int)s.labDense[s.lab[p] - 1] - chb;
        if (dl >= 0 && dl < CHUNK) s.u.cnt[dl][p] = 1;
      }
    }
    __syncthreads();
    if (tid < CHUNK && M > 0) {
      int rbN = s.recB[0], raN = s.recA[0];
      for (int m = 0; m < M; ++m) {
        int rb = rbN, ra2 = raN;
        if (m + 1 < M) { rbN = s.recB[m + 1]; raN = s.recA[m + 1]; }  // prefetch
        unsigned cb = s.u.cnt[tid][rb];
        if (cb) {
          unsigned ca = s.u.cnt[tid][ra2];
          if (ca) atomicAdd(&s.same[m], ca * cb);   // integer, order-independent
          s.u.cnt[tid][ra2] = (uint16_t)(ca + cb);
        }
      }
    }
    __syncthreads();
  }

  // ---- normalization sum S (over ALL edges, pre-mask) and masked contribution
  unsigned mys = 0u;
  for (int m = tid; m < M; m += 256)
    mys += sign ? s.same[m] : (s.totprod[m] - s.same[m]);
  atomicAdd(&s.Ssum, mys);
  __syncthreads();
  const unsigned S = s.Ssum;

  double part = 0.0;
  if (S > 0u) {
    for (int m = tid; m < M; m += 256) {
      unsigned np = sign ? s.same[m] : (s.totprod[m] - s.same[m]);
      if (np == 0u) continue;
      int e = s.recE[m];
      int cls = s.gtclass[e];
      bool keep = sign ? (cls != 0)    // ewp[gt<20]=0  -> keep cls 1,2
                       : (cls == 0);   // ewn[gt>=10]=0 -> keep cls 0
      if (!keep) continue;
      int a, b; edge_nodes(e, a, b);
      double fa, fb;
      if (sign) {
        double da = 20.0 - (double)s.Pw[a], db = 20.0 - (double)s.Pw[b];
        fa = da * da; fb = db * db;
      } else {
        fa = (double)s.Pw[a] * (double)s.Pw[a];
        fb = (double)s.Pw[b] * (double)s.Pw[b];
      }
      part += (double)np * (fa + fb);
    }
  }
  __syncthreads();           // cnt/keys region dead; reuse as red[]
  s.u.red[tid] = part;
  __syncthreads();
  for (int st = 128; st > 0; st >>= 1) {
    if (tid < st) s.u.red[tid] += s.u.red[tid + st];
    __syncthreads();
  }
  if (tid == 0) part_out[bid] = (S > 0u) ? (s.u.red[0] / (double)S) : 0.0;
}

__global__ __launch_bounds__(256) void final_reduce(
    const double* __restrict__ part, float* __restrict__ out)
{
  __shared__ double r[256];
  int t = threadIdx.x;
  r[t] = part[t];
  __syncthreads();
  for (int st = 128; st > 0; st >>= 1) {
    if (t < st) r[t] += r[t + st];
    __syncthreads();
  }
  if (t == 0) out[0] = (float)r[0];
}

extern "C" void kernel_launch(void* const* d_in, const int* in_sizes, int n_in,
                              void* d_out, int out_size, void* d_ws, size_t ws_size,
                              hipStream_t stream) {
  const float* y_true = (const float*)d_in[0];
  const float* y_pred = (const float*)d_in[1];
  double* wsd = (double*)d_ws;            // 256 doubles of scratch
  malis_kernel<<<256, 256, 0, stream>>>(y_true, y_pred, wsd);
  final_reduce<<<1, 256, 0, stream>>>(wsd, (float*)d_out);
}

// Round 5
// 661.447 us; speedup vs baseline: 2.2305x; 1.1518x over previous
//
#include <hip/hip_runtime.h>
#include <stdint.h>

#define NPIX 1024
#define NEDGE 1984
#define NSORT 2048
#define CHUNK 16
#define CNTW (NPIX + 2)   // pad rows: stride 2052B -> replay lanes hit distinct banks

struct SMem {
  union {
    unsigned long long keys[NSORT];   // 16384 B  (sort + phase1)
    uint16_t cnt[CHUNK][CNTW];        // 32832 B  (phase2 replay)
    double   red[256];                // 2048 B   (final reduction)
  } u;
  float    Pw[NPIX];          // window y_pred
  uint16_t lab[NPIX];         // CC labels (min pixel id + 1), 0 = unlabeled
  uint16_t par[NPIX];         // union-find parent
  uint32_t tot[NPIX];         // labeled-node count per root
  uint16_t labDense[NPIX];    // ACTIVE label id+1 at component-min pixel (0 = inactive)
  uint16_t recE[NPIX];        // merge records (<= 1023 used)
  uint16_t recA[NPIX];
  uint16_t recB[NPIX];
  uint32_t totprod[NPIX];     // totA*totB at merge time
  uint32_t same[NPIX];        // scratch: labCount, then same-label pairs per merge
  uint8_t  maskv[NPIX];       // T==0 (background / labeled)
  uint8_t  gtclass[NEDGE];    // # endpoints with T!=0 : 0,1,2
  unsigned int minPb, maxPb, minTb, maxTb, Ssum;
  int nlabs, Msh, changed;
};

__device__ __forceinline__ void edge_nodes(int e, int& a, int& b) {
  if (e < 992) { int r = e / 31; int c = e - r * 31; a = (r << 5) + c; b = a + 1; }
  else         { a = e - 992; b = a + 32; }
}

__global__ __launch_bounds__(256) void malis_kernel(
    const float* __restrict__ y_true, const float* __restrict__ y_pred,
    double* __restrict__ part_out)
{
  __shared__ SMem s;
  const int tid  = threadIdx.x;
  const int bid  = blockIdx.x;
  const int sign = bid & 1;          // 0 = neg, 1 = pos
  const int win  = (bid >> 1) & 63;
  const int bat  = bid >> 7;
  const int wr = win >> 3, wc = win & 7;

  if (tid == 0) {
    s.minPb = 0xFFFFFFFFu; s.maxPb = 0u; s.minTb = 0xFFFFFFFFu; s.maxTb = 0u;
    s.nlabs = 0; s.Msh = 0; s.Ssum = 0u;
  }
  __syncthreads();

  // ---- load window; min/max over BOTH batches for the exact skip predicate.
  {
    unsigned mnP = 0xFFFFFFFFu, mxP = 0u, mnT = 0xFFFFFFFFu, mxT = 0u;
    for (int i = tid; i < 2 * NPIX; i += 256) {
      int bb = i >> 10, p = i & (NPIX - 1);
      int r = p >> 5, c = p & 31;
      size_t g = ((size_t)(bb * 256 + wr * 32 + r)) * 256 + (size_t)(wc * 32 + c);
      float pv = y_pred[g], tv = y_true[g];
      unsigned pu = __float_as_uint(pv), tu = __float_as_uint(tv);
      mnP = min(mnP, pu); mxP = max(mxP, pu);
      mnT = min(mnT, tu); mxT = max(mxT, tu);
      if (bb == bat) { s.Pw[p] = pv; s.maskv[p] = (tv == 0.0f) ? 1 : 0; }
    }
    atomicMin(&s.minPb, mnP); atomicMax(&s.maxPb, mxP);   // valid: values >= 0
    atomicMin(&s.minTb, mnT); atomicMax(&s.maxTb, mxT);
  }
  __syncthreads();

  {
    float mnP = __uint_as_float(s.minPb), mxP = __uint_as_float(s.maxPb);
    float mnT = __uint_as_float(s.minTb), mxT = __uint_as_float(s.maxTb);
    if (mnP == 1.0f || mxP == 0.0f || mnT == 1.0f || mxT == 0.0f) {
      if (tid == 0) part_out[bid] = 0.0;
      return;                                   // uniform across block
    }
  }

  // ---- edge keys (cost desc, index asc  ->  pack (~bits(cost), e), sort asc)
  for (int e = tid; e < NSORT; e += 256) {
    if (e < NEDGE) {
      int a, b; edge_nodes(e, a, b);
      int cls = (s.maskv[a] ? 0 : 1) + (s.maskv[b] ? 0 : 1);
      s.gtclass[e] = (uint8_t)cls;
      float cost = s.Pw[a] + s.Pw[b];
      if (sign == 0) { if (cls == 2) cost = 20.0f; }   // costs_n[gt>20]=20
      else           { if (cls == 0) cost = 0.0f;  }   // costs_p[gt<10]=0
      s.u.keys[e] = (((unsigned long long)(__float_as_uint(cost) ^ 0xFFFFFFFFu)) << 32)
                    | (unsigned long long)(unsigned)e;
    } else {
      s.u.keys[e] = ~0ull;                             // pad sorts to end
    }
  }
  for (int p = tid; p < NPIX; p += 256) {
    s.lab[p] = s.maskv[p] ? (uint16_t)(p + 1) : (uint16_t)0;
    s.par[p] = (uint16_t)p;
    s.tot[p] = (uint32_t)s.maskv[p];
    s.same[p] = 0u;          // used first as labCount scratch
    s.totprod[p] = 0u;
  }
  __syncthreads();

  // ---- 8-connected components of maskv: monotone min-propagation + jumps
  for (;;) {
    if (tid == 0) s.changed = 0;
    __syncthreads();
    for (int p = tid; p < NPIX; p += 256) {
      if (!s.maskv[p]) continue;
      int r = p >> 5, c = p & 31;
      unsigned m = s.lab[p];
      bool up = r > 0, dn = r < 31, lf = c > 0, rt = c < 31;
      if (up) {
        if (s.maskv[p-32])       { unsigned v = s.lab[p-32]; if (v < m) m = v; }
        if (lf && s.maskv[p-33]) { unsigned v = s.lab[p-33]; if (v < m) m = v; }
        if (rt && s.maskv[p-31]) { unsigned v = s.lab[p-31]; if (v < m) m = v; }
      }
      if (dn) {
        if (s.maskv[p+32])       { unsigned v = s.lab[p+32]; if (v < m) m = v; }
        if (lf && s.maskv[p+31]) { unsigned v = s.lab[p+31]; if (v < m) m = v; }
        if (rt && s.maskv[p+33]) { unsigned v = s.lab[p+33]; if (v < m) m = v; }
      }
      if (lf && s.maskv[p-1]) { unsigned v = s.lab[p-1]; if (v < m) m = v; }
      if (rt && s.maskv[p+1]) { unsigned v = s.lab[p+1]; if (v < m) m = v; }
      unsigned m2 = s.lab[m - 1]; if (m2 && m2 < m) m = m2;   // pointer jump
      m2 = s.lab[m - 1];          if (m2 && m2 < m) m = m2;   // jump again
      if (m < (unsigned)s.lab[p]) { s.lab[p] = (uint16_t)m; s.changed = 1; }
    }
    __syncthreads();
    int ch = s.changed;
    __syncthreads();
    if (!ch) break;
  }

  // ---- label sizes (same[] as scratch); ACTIVE labels = size>=2 only.
  // Size-1 labels provably contribute 0 to same[] (ca*cb==0 always).
  for (int p = tid; p < NPIX; p += 256)
    if (s.maskv[p]) atomicAdd(&s.same[s.lab[p] - 1], 1u);
  __syncthreads();
  for (int p = tid; p < NPIX; p += 256) {
    if (s.maskv[p] && s.lab[p] == (uint16_t)(p + 1))
      s.labDense[p] = (s.same[p] >= 2u) ? (uint16_t)(atomicAdd(&s.nlabs, 1) + 1) : 0;
  }
  __syncthreads();
  for (int p = tid; p < NPIX; p += 256) s.same[p] = 0u;   // re-zero for replay
  __syncthreads();

  // ---- bitonic sort (ascending) of 2048 keys, 256 threads
  for (int k = 2; k <= NSORT; k <<= 1) {
    for (int j = k >> 1; j > 0; j >>= 1) {
      __syncthreads();
      for (int i = tid; i < NSORT; i += 256) {
        int ixj = i ^ j;
        if (ixj > i) {
          unsigned long long A = s.u.keys[i], B = s.u.keys[ixj];
          bool asc = ((i & k) == 0);
          if ((A > B) == asc) { s.u.keys[i] = B; s.u.keys[ixj] = A; }
        }
      }
    }
  }
  __syncthreads();

  // ---- phase 1: wave-cooperative batch Kruskal (wave 0 only).
  // Per 64-edge batch: read-only speculative root walks, candidate ballot,
  // then serial resolution with ALWAYS-CURRENT mTo invariant:
  //   - every merge rB->rA updates all lanes' mTo==rB to rA (1 VALU op)
  //   - so chase = ONE ballot(mFrom==r) + readlane (mFrom values unique)
  //   - current size of r's component = szTo of HIGHEST lane in ballot(mTo==r)
  // All ballots/readlanes in uniform control flow (CDNA exec-mask rule).
  if (tid < 64) {
    const int lane = tid;
    int mTotal = 0;                       // emitted record count (uniform)
    for (int base = 0; base < NSORT; base += 64) {
      // step A: speculative read-only finds against batch-start forest
      unsigned long long key = s.u.keys[base + lane];
      unsigned e = (unsigned)key;
      int ra = 0, rb = 0; unsigned sa = 0, sb = 0;
      bool valid = (e < (unsigned)NEDGE);
      if (valid) {
        int a, b; edge_nodes((int)e, a, b);
        int xa = a, xb = b;
        for (;;) {
          int pa = s.par[xa], pb = s.par[xb];   // dual walk: overlap latency
          if (pa == xa && pb == xb) break;
          xa = pa; xb = pb;                     // roots self-loop: safe
        }
        ra = xa; rb = xb;
        sa = s.tot[ra]; sb = s.tot[rb];
      }
      bool cand = valid && (ra != rb);
      unsigned long long cm = __ballot(cand);
      // pack: w0 = ra(10) | rb(10) | e(11);  w1 = sa(11) | sb(11)
      unsigned w0 = (unsigned)ra | ((unsigned)rb << 10) | (e << 20);
      unsigned w1 = sa | (sb << 11);

      // step B: serial resolution over candidate lanes only
      int mb = 0;                                  // merges this batch
      int mFrom = -1, mTo = -1; unsigned szTo = 0; // my merge slot (registers)
      while (cm) {
        int i = __ffsll((long long)cm) - 1;
        cm &= cm - 1;
        unsigned W0 = (unsigned)__builtin_amdgcn_readlane((int)w0, i);
        unsigned W1 = (unsigned)__builtin_amdgcn_readlane((int)w1, i);
        int rA = (int)(W0 & 1023u);
        int rB = (int)((W0 >> 10) & 1023u);
        unsigned eI = W0 >> 20;
        unsigned sA = W1 & 2047u;
        unsigned sB = W1 >> 11;
        // O(1) chase: absorbed batch-start roots appear as a unique mFrom,
        // whose mTo is the CURRENT root (invariant).
        {
          unsigned long long mm = __ballot(mFrom == rA);
          if (mm) rA = __builtin_amdgcn_readlane(mTo, __ffsll((long long)mm) - 1);
          mm = __ballot(mFrom == rB);
          if (mm) rB = __builtin_amdgcn_readlane(mTo, __ffsll((long long)mm) - 1);
        }
        if (rA == rB) continue;
        // current sizes: highest slot with mTo==r holds current size of r
        {
          unsigned long long ma = __ballot(mTo == rA);
          if (ma) sA = (unsigned)__builtin_amdgcn_readlane((int)szTo, 63 - __clzll((long long)ma));
          unsigned long long mbm = __ballot(mTo == rB);
          if (mbm) sB = (unsigned)__builtin_amdgcn_readlane((int)szTo, 63 - __clzll((long long)mbm));
        }
        // record merge in slot mb (lane mb's registers)
        if (lane == mb) { mFrom = rB; mTo = rA; szTo = sA + sB; }
        // maintain invariant: all stale mTo==rB become rA (new slot has rA already)
        if (mTo == rB) mTo = rA;
        ++mb;
        // fire-and-forget LDS updates (no dependent reads on critical path)
        if (lane == 0) {
          s.par[rB] = (uint16_t)rA;                  // reference orientation
          atomicAdd(&s.tot[rA], sB);
          if (sB > 0) {
            s.recE[mTotal] = (uint16_t)eI;
            s.recA[mTotal] = (uint16_t)rA;
            s.recB[mTotal] = (uint16_t)rB;
            s.totprod[mTotal] = sA * sB;
          }
        }
        if (sB > 0) ++mTotal;                        // uniform
      }

      // batched pointer-jump compression: 2 passes, pipelined (load-all /
      // gather-all / store-all), one write per distinct node.
      if (mb && (base + 64 < NSORT)) {
        for (int pass = 0; pass < 2; ++pass) {
          uint16_t vv[16];
          #pragma unroll
          for (int j = 0; j < 16; ++j) vv[j] = s.par[j * 64 + lane];
          #pragma unroll
          for (int j = 0; j < 16; ++j) vv[j] = s.par[vv[j]];
          #pragma unroll
          for (int j = 0; j < 16; ++j) s.par[j * 64 + lane] = vv[j];
        }
      }
    }
    if (lane == 0) s.Msh = mTotal;
  }
  __syncthreads();

  const int M = s.Msh;
  const int nlab = s.nlabs;    // ACTIVE labels only

  // ---- phase 2: replay merge list per active label (CHUNK labels at a time)
  for (int chb = 0; chb < nlab; chb += CHUNK) {
    for (int i = tid; i < (CHUNK * CNTW) / 2; i += 256) ((uint32_t*)s.u.cnt)[i] = 0u;
    __syncthreads();
    for (int p = tid; p < NPIX; p += 256) {
      if (s.maskv[p]) {
        int dl = (int)s.labDense[s.lab[p] - 1] - 1 - chb;   // active id or <0
        if (dl >= 0 && dl < CHUNK) s.u.cnt[dl][p] = 1;
      }
    }
    __syncthreads();
    if (tid < CHUNK && M > 0) {
      int rbN = s.recB[0], raN = s.recA[0];
      for (int m = 0; m < M; ++m) {
        int rb = rbN, ra2 = raN;
        if (m + 1 < M) { rbN = s.recB[m + 1]; raN = s.recA[m + 1]; }  // prefetch
        unsigned cb = s.u.cnt[tid][rb];
        if (cb) {
          unsigned ca = s.u.cnt[tid][ra2];
          if (ca) atomicAdd(&s.same[m], ca * cb);   // integer, order-independent
          s.u.cnt[tid][ra2] = (uint16_t)(ca + cb);
        }
      }
    }
    __syncthreads();
  }

  // ---- normalization sum S (over ALL edges, pre-mask) and masked contribution
  unsigned mys = 0u;
  for (int m = tid; m < M; m += 256)
    mys += sign ? s.same[m] : (s.totprod[m] - s.same[m]);
  atomicAdd(&s.Ssum, mys);
  __syncthreads();
  const unsigned S = s.Ssum;

  double part = 0.0;
  if (S > 0u) {
    for (int m = tid; m < M; m += 256) {
      unsigned np = sign ? s.same[m] : (s.totprod[m] - s.same[m]);
      if (np == 0u) continue;
      int e = s.recE[m];
      int cls = s.gtclass[e];
      bool keep = sign ? (cls != 0)    // ewp[gt<20]=0  -> keep cls 1,2
                       : (cls == 0);   // ewn[gt>=10]=0 -> keep cls 0
      if (!keep) continue;
      int a, b; edge_nodes(e, a, b);
      double fa, fb;
      if (sign) {
        double da = 20.0 - (double)s.Pw[a], db = 20.0 - (double)s.Pw[b];
        fa = da * da; fb = db * db;
      } else {
        fa = (double)s.Pw[a] * (double)s.Pw[a];
        fb = (double)s.Pw[b] * (double)s.Pw[b];
      }
      part += (double)np * (fa + fb);
    }
  }
  __syncthreads();           // cnt/keys region dead; reuse as red[]
  s.u.red[tid] = part;
  __syncthreads();
  for (int st = 128; st > 0; st >>= 1) {
    if (tid < st) s.u.red[tid] += s.u.red[tid + st];
    __syncthreads();
  }
  if (tid == 0) part_out[bid] = (S > 0u) ? (s.u.red[0] / (double)S) : 0.0;
}

__global__ __launch_bounds__(256) void final_reduce(
    const double* __restrict__ part, float* __restrict__ out)
{
  __shared__ double r[256];
  int t = threadIdx.x;
  r[t] = part[t];
  __syncthreads();
  for (int st = 128; st > 0; st >>= 1) {
    if (t < st) r[t] += r[t + st];
    __syncthreads();
  }
  if (t == 0) out[0] = (float)r[0];
}

extern "C" void kernel_launch(void* const* d_in, const int* in_sizes, int n_in,
                              void* d_out, int out_size, void* d_ws, size_t ws_size,
                              hipStream_t stream) {
  const float* y_true = (const float*)d_in[0];
  const float* y_pred = (const float*)d_in[1];
  double* wsd = (double*)d_ws;            // 256 doubles of scratch
  malis_kernel<<<256, 256, 0, stream>>>(y_true, y_pred, wsd);
  final_reduce<<<1, 256, 0, stream>>>(wsd, (float*)d_out);
}

// Round 6
// 656.235 us; speedup vs baseline: 2.2482x; 1.0079x over previous
//
#include <hip/hip_runtime.h>
#include <stdint.h>

#define NPIX 1024
#define NEDGE 1984
#define NSORT 2048
#define CHUNK 16
#define CNTW (NPIX + 2)   // pad rows: replay lanes hit distinct banks

// ---- d_ws layout (total ~3.15 MB) ----
#define WS_PART   0u          // f64[256]   per-task loss partials
#define WS_SKIP   2048u       // u32[64]    per-window skip flag (sign/bat-indep)
#define WS_NLAB   2304u       // u32[128]   per (bat,win) active-label count
#define WS_M      2816u       // u32[256]   per-task record count
#define WS_PW     4096u       // f32[128*1024]
#define WS_LAB    528384u     // u16[128*1024]  CC labels (min-pixel-id+1, 0=bg)
#define WS_LABD   790528u     // u16[128*1024]  active dense id+1 at min pixel
#define WS_REC    1052672u    // u32[256*1024]  packed e(11)|ra(10)|rb(10)
#define WS_TOTP   2101248u    // u32[256*1024]  |A|*|B| per record

__device__ __forceinline__ void edge_nodes(int e, int& a, int& b) {
  if (e < 992) { int r = e / 31; int c = e - r * 31; a = (r << 5) + c; b = a + 1; }
  else         { a = e - 992; b = a + 32; }
}

// ============ K1: load + skip predicate + 8-conn CC + label census ============
__global__ __launch_bounds__(256) void k1_prep(const float* __restrict__ y_true,
                                               const float* __restrict__ y_pred,
                                               char* __restrict__ ws) {
  __shared__ float    Pw[NPIX];
  __shared__ uint16_t lab[NPIX];
  __shared__ uint8_t  maskv[NPIX];
  __shared__ uint32_t lcnt[NPIX];
  __shared__ unsigned minP, maxP, minT, maxT;
  __shared__ int nl, changed;
  const int tid = threadIdx.x, pw = blockIdx.x, bat = pw >> 6, win = pw & 63;
  const int wr = win >> 3, wc = win & 7;
  if (tid == 0) { minP = ~0u; maxP = 0u; minT = ~0u; maxT = 0u; nl = 0; }
  __syncthreads();
  {
    unsigned mnP = ~0u, mxP = 0u, mnT = ~0u, mxT = 0u;
    for (int i = tid; i < 2 * NPIX; i += 256) {
      int bb = i >> 10, p = i & (NPIX - 1);
      int r = p >> 5, c = p & 31;
      size_t g = ((size_t)(bb * 256 + wr * 32 + r)) * 256 + (size_t)(wc * 32 + c);
      float pv = y_pred[g], tv = y_true[g];
      unsigned pu = __float_as_uint(pv), tu = __float_as_uint(tv);
      mnP = min(mnP, pu); mxP = max(mxP, pu);
      mnT = min(mnT, tu); mxT = max(mxT, tu);
      if (bb == bat) {
        Pw[p] = pv; maskv[p] = (tv == 0.f) ? 1 : 0;
        lab[p] = (tv == 0.f) ? (uint16_t)(p + 1) : (uint16_t)0;
        lcnt[p] = 0u;
      }
    }
    atomicMin(&minP, mnP); atomicMax(&maxP, mxP);   // valid: values >= 0
    atomicMin(&minT, mnT); atomicMax(&maxT, mxT);
  }
  __syncthreads();
  {
    float a = __uint_as_float(minP), b = __uint_as_float(maxP);
    float c2 = __uint_as_float(minT), d = __uint_as_float(maxT);
    int skip = (a == 1.f || b == 0.f || c2 == 1.f || d == 0.f) ? 1 : 0;
    if (tid == 0) ((uint32_t*)(ws + WS_SKIP))[win] = (uint32_t)skip;  // dup write: same value
    if (skip) return;
  }
  // CC: monotone min-propagation + pointer jumps (proven in R1-R5)
  for (;;) {
    if (tid == 0) changed = 0;
    __syncthreads();
    for (int p = tid; p < NPIX; p += 256) {
      if (!maskv[p]) continue;
      int r = p >> 5, c = p & 31;
      unsigned m = lab[p];
      bool up = r > 0, dn = r < 31, lf = c > 0, rt = c < 31;
      if (up) {
        if (maskv[p-32])       { unsigned v = lab[p-32]; if (v < m) m = v; }
        if (lf && maskv[p-33]) { unsigned v = lab[p-33]; if (v < m) m = v; }
        if (rt && maskv[p-31]) { unsigned v = lab[p-31]; if (v < m) m = v; }
      }
      if (dn) {
        if (maskv[p+32])       { unsigned v = lab[p+32]; if (v < m) m = v; }
        if (lf && maskv[p+31]) { unsigned v = lab[p+31]; if (v < m) m = v; }
        if (rt && maskv[p+33]) { unsigned v = lab[p+33]; if (v < m) m = v; }
      }
      if (lf && maskv[p-1]) { unsigned v = lab[p-1]; if (v < m) m = v; }
      if (rt && maskv[p+1]) { unsigned v = lab[p+1]; if (v < m) m = v; }
      unsigned m2 = lab[m - 1]; if (m2 && m2 < m) m = m2;
      m2 = lab[m - 1];          if (m2 && m2 < m) m = m2;
      if (m < (unsigned)lab[p]) { lab[p] = (uint16_t)m; changed = 1; }
    }
    __syncthreads();
    int ch = changed;
    __syncthreads();
    if (!ch) break;
  }
  // label sizes; active = size>=2 (size-1 labels contribute 0 to same[])
  for (int p = tid; p < NPIX; p += 256)
    if (maskv[p]) atomicAdd(&lcnt[lab[p] - 1], 1u);
  __syncthreads();
  uint16_t* labDG = (uint16_t*)(ws + WS_LABD) + (size_t)pw * NPIX;
  for (int p = tid; p < NPIX; p += 256) {
    uint16_t v = 0;
    if (maskv[p] && lab[p] == (uint16_t)(p + 1) && lcnt[p] >= 2u)
      v = (uint16_t)(atomicAdd(&nl, 1) + 1);
    labDG[p] = v;
  }
  __syncthreads();
  float*    PwG  = (float*)(ws + WS_PW)  + (size_t)pw * NPIX;
  uint16_t* labG = (uint16_t*)(ws + WS_LAB) + (size_t)pw * NPIX;
  for (int p = tid; p < NPIX; p += 256) { PwG[p] = Pw[p]; labG[p] = lab[p]; }
  if (tid == 0) ((uint32_t*)(ws + WS_NLAB))[pw] = (uint32_t)nl;
}

// ============ K2: edge keys + bitonic sort + wave-cooperative Kruskal ============
__global__ __launch_bounds__(256) void k2_sortkruskal(char* __restrict__ ws) {
  __shared__ unsigned long long keys[NSORT];   // 16 KB
  __shared__ float    Pw[NPIX];
  __shared__ uint16_t lab[NPIX];
  __shared__ uint16_t par[NPIX];
  __shared__ uint16_t tot[NPIX];
  const int tid = threadIdx.x, t = blockIdx.x;
  const int sign = t & 1, win = (t >> 1) & 63, bat = t >> 7;
  const int pw = bat * 64 + win;
  uint32_t* MG = (uint32_t*)(ws + WS_M);
  if (((const uint32_t*)(ws + WS_SKIP))[win]) { if (tid == 0) MG[t] = 0u; return; }

  const float*    PwG  = (const float*)(ws + WS_PW)  + (size_t)pw * NPIX;
  const uint16_t* labG = (const uint16_t*)(ws + WS_LAB) + (size_t)pw * NPIX;
  for (int p = tid; p < NPIX; p += 256) {
    float pv = PwG[p]; uint16_t l = labG[p];
    Pw[p] = pv; lab[p] = l; par[p] = (uint16_t)p; tot[p] = l ? 1 : 0;
  }
  __syncthreads();
  for (int e = tid; e < NSORT; e += 256) {
    if (e < NEDGE) {
      int a, b; edge_nodes(e, a, b);
      int cls = (lab[a] ? 0 : 1) + (lab[b] ? 0 : 1);
      float cost = Pw[a] + Pw[b];
      if (sign == 0) { if (cls == 2) cost = 20.0f; }   // costs_n[gt>20]=20
      else           { if (cls == 0) cost = 0.0f;  }   // costs_p[gt<10]=0
      keys[e] = (((unsigned long long)(__float_as_uint(cost) ^ 0xFFFFFFFFu)) << 32)
                | (unsigned long long)(unsigned)e;
    } else keys[e] = ~0ull;
  }
  // bitonic sort ascending (cost desc, index asc)
  for (int k = 2; k <= NSORT; k <<= 1) {
    for (int j = k >> 1; j > 0; j >>= 1) {
      __syncthreads();
      for (int i = tid; i < NSORT; i += 256) {
        int ixj = i ^ j;
        if (ixj > i) {
          unsigned long long A = keys[i], B = keys[ixj];
          bool asc = ((i & k) == 0);
          if ((A > B) == asc) { keys[i] = B; keys[ixj] = A; }
        }
      }
    }
  }
  __syncthreads();

  // wave-cooperative batch Kruskal (wave 0): R5-proven logic, records -> ws.
  // All ballots/readlanes in uniform control flow (CDNA exec-mask rule).
  if (tid < 64) {
    const int lane = tid;
    uint32_t* recG = (uint32_t*)(ws + WS_REC)  + (size_t)t * NPIX;
    uint32_t* totG = (uint32_t*)(ws + WS_TOTP) + (size_t)t * NPIX;
    int mTotal = 0;
    for (int base = 0; base < NSORT; base += 64) {
      unsigned long long key = keys[base + lane];
      unsigned e = (unsigned)key;
      int ra = 0, rb = 0; unsigned sa = 0, sb = 0;
      bool valid = (e < (unsigned)NEDGE);
      if (valid) {
        int a, b; edge_nodes((int)e, a, b);
        int xa = a, xb = b;
        for (;;) {
          int pa = par[xa], pb = par[xb];
          if (pa == xa && pb == xb) break;
          xa = pa; xb = pb;
        }
        ra = xa; rb = xb;
        sa = tot[ra]; sb = tot[rb];
      }
      bool cand = valid && (ra != rb);
      unsigned long long cm = __ballot(cand);
      unsigned w0 = (unsigned)ra | ((unsigned)rb << 10) | (e << 20);
      unsigned w1 = sa | (sb << 11);

      int mb = 0;
      int mFrom = -1, mTo = -1; unsigned szTo = 0;
      while (cm) {
        int i = __ffsll((long long)cm) - 1;
        cm &= cm - 1;
        unsigned W0 = (unsigned)__builtin_amdgcn_readlane((int)w0, i);
        unsigned W1 = (unsigned)__builtin_amdgcn_readlane((int)w1, i);
        int rA = (int)(W0 & 1023u);
        int rB = (int)((W0 >> 10) & 1023u);
        unsigned eI = W0 >> 20;
        unsigned sA = W1 & 2047u;
        unsigned sB = W1 >> 11;
        {  // O(1) chase via always-current mTo invariant
          unsigned long long mm = __ballot(mFrom == rA);
          if (mm) rA = __builtin_amdgcn_readlane(mTo, __ffsll((long long)mm) - 1);
          mm = __ballot(mFrom == rB);
          if (mm) rB = __builtin_amdgcn_readlane(mTo, __ffsll((long long)mm) - 1);
        }
        if (rA == rB) continue;
        {  // current sizes: highest slot with mTo==r holds current size
          unsigned long long ma = __ballot(mTo == rA);
          if (ma) sA = (unsigned)__builtin_amdgcn_readlane((int)szTo, 63 - __clzll((long long)ma));
          unsigned long long mbm = __ballot(mTo == rB);
          if (mbm) sB = (unsigned)__builtin_amdgcn_readlane((int)szTo, 63 - __clzll((long long)mbm));
        }
        if (lane == mb) { mFrom = rB; mTo = rA; szTo = sA + sB; }
        if (mTo == rB) mTo = rA;            // maintain invariant
        ++mb;
        if (lane == 0) {
          par[rB] = (uint16_t)rA;           // reference orientation
          tot[rA] = (uint16_t)(sA + sB);    // single writer: plain store
          if (sB > 0) {
            recG[mTotal] = eI | ((unsigned)rA << 11) | ((unsigned)rB << 21);
            totG[mTotal] = sA * sB;
          }
        }
        if (sB > 0) ++mTotal;               // uniform
      }
      // batched pointer-jump compression (conflict-free: 1 write/node)
      if (mb && (base + 64 < NSORT)) {
        for (int pass = 0; pass < 2; ++pass) {
          uint16_t vv[16];
          #pragma unroll
          for (int j = 0; j < 16; ++j) vv[j] = par[j * 64 + lane];
          #pragma unroll
          for (int j = 0; j < 16; ++j) vv[j] = par[vv[j]];
          #pragma unroll
          for (int j = 0; j < 16; ++j) par[j * 64 + lane] = vv[j];
        }
      }
    }
    if (lane == 0) MG[t] = (uint32_t)mTotal;
  }
}

// ============ K3: per-label replay (register run-cache) + loss epilogue ============
__global__ __launch_bounds__(256) void k3_replay(char* __restrict__ ws) {
  __shared__ union {
    uint16_t cnt[CHUNK][CNTW];   // 32832 B
    double   red[256];
  } u;
  __shared__ uint32_t recW[NPIX];
  __shared__ uint32_t totp[NPIX];
  __shared__ uint32_t same[NPIX];
  __shared__ float    Pw[NPIX];
  __shared__ uint16_t lab[NPIX];
  __shared__ uint16_t labD[NPIX];
  __shared__ unsigned Ssum;
  const int tid = threadIdx.x, t = blockIdx.x;
  const int sign = t & 1, win = (t >> 1) & 63, bat = t >> 7;
  const int pw = bat * 64 + win;
  double* partG = (double*)(ws + WS_PART);
  if (((const uint32_t*)(ws + WS_SKIP))[win]) { if (tid == 0) partG[t] = 0.0; return; }
  const int M    = (int)((const uint32_t*)(ws + WS_M))[t];
  const int nlab = (int)((const uint32_t*)(ws + WS_NLAB))[pw];
  {
    const uint32_t* recG  = (const uint32_t*)(ws + WS_REC)  + (size_t)t * NPIX;
    const uint32_t* totG  = (const uint32_t*)(ws + WS_TOTP) + (size_t)t * NPIX;
    const float*    PwG   = (const float*)(ws + WS_PW)   + (size_t)pw * NPIX;
    const uint16_t* labG  = (const uint16_t*)(ws + WS_LAB)  + (size_t)pw * NPIX;
    const uint16_t* labDG = (const uint16_t*)(ws + WS_LABD) + (size_t)pw * NPIX;
    for (int m = tid; m < M; m += 256) { recW[m] = recG[m]; totp[m] = totG[m]; same[m] = 0u; }
    for (int p = tid; p < NPIX; p += 256) { Pw[p] = PwG[p]; lab[p] = labG[p]; labD[p] = labDG[p]; }
  }
  if (tid == 0) Ssum = 0u;
  __syncthreads();

  for (int chb = 0; chb < nlab; chb += CHUNK) {
    for (int i = tid; i < (CHUNK * CNTW) / 2; i += 256) ((uint32_t*)u.cnt)[i] = 0u;
    __syncthreads();
    for (int p = tid; p < NPIX; p += 256) {
      if (lab[p]) {
        int dl = (int)labD[lab[p] - 1] - 1 - chb;   // active id or <0
        if (dl >= 0 && dl < CHUNK) u.cnt[dl][p] = 1;
      }
    }
    __syncthreads();
    // serial replay, 16 label-lanes; register run-cache on consecutive equal rA:
    // sequential semantics == R5 (cb=cnt[rb]; if cb {same+=ca*cb; cnt[ra]+=cb})
    if (tid < CHUNK && M > 0) {
      int lastRa = -1; unsigned lastVal = 0;
      for (int m = 0; m < M; ++m) {
        unsigned w = recW[m];
        int ra = (int)((w >> 11) & 1023u), rb = (int)(w >> 21);
        unsigned cb;
        if (ra != lastRa) {
          int fr = lastRa; unsigned fv = lastVal;
          if (fr >= 0) u.cnt[tid][fr] = (uint16_t)fv;  // flush old run
          lastVal = u.cnt[tid][ra];                    // fresh (ra != fr)
          lastRa = ra;
          cb = (rb == fr) ? fv : u.cnt[tid][rb];       // absorbed old run?
        } else {
          cb = u.cnt[tid][rb];                         // rb != lastRa: LDS fresh
        }
        if (cb) {
          if (lastVal) atomicAdd(&same[m], lastVal * cb);
          lastVal += cb;
        }
      }
      // no final flush needed: cnt re-zeroed next chunk
    }
    __syncthreads();
  }

  // normalization sum S and masked loss contribution
  unsigned mys = 0u;
  for (int m = tid; m < M; m += 256)
    mys += sign ? same[m] : (totp[m] - same[m]);
  atomicAdd(&Ssum, mys);
  __syncthreads();
  const unsigned S = Ssum;

  double part = 0.0;
  if (S > 0u) {
    for (int m = tid; m < M; m += 256) {
      unsigned np = sign ? same[m] : (totp[m] - same[m]);
      if (np == 0u) continue;
      int e = (int)(recW[m] & 2047u);
      int a, b; edge_nodes(e, a, b);
      int cls = (lab[a] ? 0 : 1) + (lab[b] ? 0 : 1);
      bool keep = sign ? (cls != 0)    // ewp[gt<20]=0 -> keep cls 1,2
                       : (cls == 0);   // ewn[gt>=10]=0 -> keep cls 0
      if (!keep) continue;
      double fa, fb;
      if (sign) {
        double da = 20.0 - (double)Pw[a], db = 20.0 - (double)Pw[b];
        fa = da * da; fb = db * db;
      } else {
        fa = (double)Pw[a] * (double)Pw[a];
        fb = (double)Pw[b] * (double)Pw[b];
      }
      part += (double)np * (fa + fb);
    }
  }
  u.red[tid] = part;       // cnt region dead (chunk loop ended with barrier)
  __syncthreads();
  for (int st = 128; st > 0; st >>= 1) {
    if (tid < st) u.red[tid] += u.red[tid + st];
    __syncthreads();
  }
  if (tid == 0) partG[t] = (S > 0u) ? (u.red[0] / (double)S) : 0.0;
}

__global__ __launch_bounds__(256) void final_reduce(
    const double* __restrict__ part, float* __restrict__ out)
{
  __shared__ double r[256];
  int tdx = threadIdx.x;
  r[tdx] = part[tdx];
  __syncthreads();
  for (int st = 128; st > 0; st >>= 1) {
    if (tdx < st) r[tdx] += r[tdx + st];
    __syncthreads();
  }
  if (tdx == 0) out[0] = (float)r[0];
}

extern "C" void kernel_launch(void* const* d_in, const int* in_sizes, int n_in,
                              void* d_out, int out_size, void* d_ws, size_t ws_size,
                              hipStream_t stream) {
  const float* y_true = (const float*)d_in[0];
  const float* y_pred = (const float*)d_in[1];
  char* ws = (char*)d_ws;
  k1_prep<<<128, 256, 0, stream>>>(y_true, y_pred, ws);
  k2_sortkruskal<<<256, 256, 0, stream>>>(ws);
  k3_replay<<<256, 256, 0, stream>>>(ws);
  final_reduce<<<1, 256, 0, stream>>>((const double*)(ws + WS_PART), (float*)d_out);
}

// Round 7
// 639.277 us; speedup vs baseline: 2.3078x; 1.0265x over previous
//
#include <hip/hip_runtime.h>
#include <stdint.h>

#define NPIX 1024
#define NEDGE 1984
#define NSORT 2048
#define CHUNK 16
#define CNTW (NPIX + 2)   // pad rows: replay lanes hit distinct banks

// ---- d_ws layout (total ~4.0 MB) ----
#define WS_PART   0u          // f64[256]   per-task loss partials
#define WS_SKIP   2048u       // u32[64]    per-window skip flag
#define WS_NLAB   2304u       // u32[128]   per (bat,win) active-label count
#define WS_M      2816u       // u32[256]   per-task record count
#define WS_PW     4096u       // f32[128*1024]
#define WS_LAB    528384u     // u16[128*1024]  CC labels (min-pixel-id+1, 0=bg)
#define WS_LABD   790528u     // u16[128*1024]  active dense id+1 at min pixel
#define WS_REC    1052672u    // u32[256*1024]  packed e(11)|ra(10)|rb(10)
#define WS_TOTP   2101248u    // u32[256*1024]  |A|*|B| per record
#define WS_ORD    3149824u    // u16[256*2048]  sorted edge order per task

__device__ __forceinline__ void edge_nodes(int e, int& a, int& b) {
  if (e < 992) { int r = e / 31; int c = e - r * 31; a = (r << 5) + c; b = a + 1; }
  else         { a = e - 992; b = a + 32; }
}

// ============ K1: load + skip predicate + 8-conn CC + label census ============
__global__ __launch_bounds__(256) void k1_prep(const float* __restrict__ y_true,
                                               const float* __restrict__ y_pred,
                                               char* __restrict__ ws) {
  __shared__ float    Pw[NPIX];
  __shared__ uint16_t lab[NPIX];
  __shared__ uint8_t  maskv[NPIX];
  __shared__ uint32_t lcnt[NPIX];
  __shared__ unsigned minP, maxP, minT, maxT;
  __shared__ int nl, changed;
  const int tid = threadIdx.x, pw = blockIdx.x, bat = pw >> 6, win = pw & 63;
  const int wr = win >> 3, wc = win & 7;
  if (tid == 0) { minP = ~0u; maxP = 0u; minT = ~0u; maxT = 0u; nl = 0; }
  __syncthreads();
  {
    unsigned mnP = ~0u, mxP = 0u, mnT = ~0u, mxT = 0u;
    for (int i = tid; i < 2 * NPIX; i += 256) {
      int bb = i >> 10, p = i & (NPIX - 1);
      int r = p >> 5, c = p & 31;
      size_t g = ((size_t)(bb * 256 + wr * 32 + r)) * 256 + (size_t)(wc * 32 + c);
      float pv = y_pred[g], tv = y_true[g];
      unsigned pu = __float_as_uint(pv), tu = __float_as_uint(tv);
      mnP = min(mnP, pu); mxP = max(mxP, pu);
      mnT = min(mnT, tu); mxT = max(mxT, tu);
      if (bb == bat) {
        Pw[p] = pv; maskv[p] = (tv == 0.f) ? 1 : 0;
        lab[p] = (tv == 0.f) ? (uint16_t)(p + 1) : (uint16_t)0;
        lcnt[p] = 0u;
      }
    }
    atomicMin(&minP, mnP); atomicMax(&maxP, mxP);   // valid: values >= 0
    atomicMin(&minT, mnT); atomicMax(&maxT, mxT);
  }
  __syncthreads();
  {
    float a = __uint_as_float(minP), b = __uint_as_float(maxP);
    float c2 = __uint_as_float(minT), d = __uint_as_float(maxT);
    int skip = (a == 1.f || b == 0.f || c2 == 1.f || d == 0.f) ? 1 : 0;
    if (tid == 0) ((uint32_t*)(ws + WS_SKIP))[win] = (uint32_t)skip;  // dup write: same value
    if (skip) return;
  }
  for (;;) {
    if (tid == 0) changed = 0;
    __syncthreads();
    for (int p = tid; p < NPIX; p += 256) {
      if (!maskv[p]) continue;
      int r = p >> 5, c = p & 31;
      unsigned m = lab[p];
      bool up = r > 0, dn = r < 31, lf = c > 0, rt = c < 31;
      if (up) {
        if (maskv[p-32])       { unsigned v = lab[p-32]; if (v < m) m = v; }
        if (lf && maskv[p-33]) { unsigned v = lab[p-33]; if (v < m) m = v; }
        if (rt && maskv[p-31]) { unsigned v = lab[p-31]; if (v < m) m = v; }
      }
      if (dn) {
        if (maskv[p+32])       { unsigned v = lab[p+32]; if (v < m) m = v; }
        if (lf && maskv[p+31]) { unsigned v = lab[p+31]; if (v < m) m = v; }
        if (rt && maskv[p+33]) { unsigned v = lab[p+33]; if (v < m) m = v; }
      }
      if (lf && maskv[p-1]) { unsigned v = lab[p-1]; if (v < m) m = v; }
      if (rt && maskv[p+1]) { unsigned v = lab[p+1]; if (v < m) m = v; }
      unsigned m2 = lab[m - 1]; if (m2 && m2 < m) m = m2;
      m2 = lab[m - 1];          if (m2 && m2 < m) m = m2;
      if (m < (unsigned)lab[p]) { lab[p] = (uint16_t)m; changed = 1; }
    }
    __syncthreads();
    int ch = changed;
    __syncthreads();
    if (!ch) break;
  }
  for (int p = tid; p < NPIX; p += 256)
    if (maskv[p]) atomicAdd(&lcnt[lab[p] - 1], 1u);
  __syncthreads();
  uint16_t* labDG = (uint16_t*)(ws + WS_LABD) + (size_t)pw * NPIX;
  for (int p = tid; p < NPIX; p += 256) {
    uint16_t v = 0;
    if (maskv[p] && lab[p] == (uint16_t)(p + 1) && lcnt[p] >= 2u)
      v = (uint16_t)(atomicAdd(&nl, 1) + 1);
    labDG[p] = v;
  }
  __syncthreads();
  float*    PwG  = (float*)(ws + WS_PW)  + (size_t)pw * NPIX;
  uint16_t* labG = (uint16_t*)(ws + WS_LAB) + (size_t)pw * NPIX;
  for (int p = tid; p < NPIX; p += 256) { PwG[p] = Pw[p]; labG[p] = lab[p]; }
  if (tid == 0) ((uint32_t*)(ws + WS_NLAB))[pw] = (uint32_t)nl;
}

// ============ K2a: edge keys + register-fused bitonic sort -> order to ws ============
__global__ __launch_bounds__(256) void k2a_sort(char* __restrict__ ws) {
  __shared__ unsigned long long sk[NSORT];   // 16 KB
  __shared__ float    Pw[NPIX];
  __shared__ uint16_t lab[NPIX];
  const int tid = threadIdx.x, t = blockIdx.x;
  const int sign = t & 1, win = (t >> 1) & 63, bat = t >> 7;
  const int pw = bat * 64 + win;
  if (((const uint32_t*)(ws + WS_SKIP))[win]) return;
  const float*    PwG  = (const float*)(ws + WS_PW)  + (size_t)pw * NPIX;
  const uint16_t* labG = (const uint16_t*)(ws + WS_LAB) + (size_t)pw * NPIX;
  for (int p = tid; p < NPIX; p += 256) { Pw[p] = PwG[p]; lab[p] = labG[p]; }
  __syncthreads();
  for (int e = tid; e < NSORT; e += 256) {
    if (e < NEDGE) {
      int a, b; edge_nodes(e, a, b);
      int cls = (lab[a] ? 0 : 1) + (lab[b] ? 0 : 1);
      float cost = Pw[a] + Pw[b];
      if (sign == 0) { if (cls == 2) cost = 20.0f; }   // costs_n[gt>20]=20
      else           { if (cls == 0) cost = 0.0f;  }   // costs_p[gt<10]=0
      sk[e] = (((unsigned long long)(__float_as_uint(cost) ^ 0xFFFFFFFFu)) << 32)
              | (unsigned long long)(unsigned)e;
    } else sk[e] = ~0ull;
  }
  __syncthreads();
  // phase A: k=2,4,8 fully in registers (thread owns 8 consecutive elements)
  {
    unsigned long long x[8];
    const int baseI = tid * 8;
    #pragma unroll
    for (int v = 0; v < 8; ++v) x[v] = sk[baseI + v];
    #pragma unroll
    for (int kk = 2; kk <= 8; kk <<= 1) {
      #pragma unroll
      for (int j = kk >> 1; j > 0; j >>= 1) {
        #pragma unroll
        for (int v = 0; v < 8; ++v) {
          int p = v ^ j;
          if (p > v) {
            bool asc = (((baseI + v) & kk) == 0);
            unsigned long long A = x[v], B = x[p];
            if ((A > B) == asc) { x[v] = B; x[p] = A; }
          }
        }
      }
    }
    #pragma unroll
    for (int v = 0; v < 8; ++v) sk[baseI + v] = x[v];
  }
  // phases k=16..2048: LDS rounds for j>=8 (active-pair mapping), register tail j=4,2,1
  for (int k = 16; k <= NSORT; k <<= 1) {
    for (int j = k >> 1; j >= 8; j >>= 1) {
      __syncthreads();
      for (int q = tid; q < NSORT / 2; q += 256) {
        int i = ((q & ~(j - 1)) << 1) | (q & (j - 1));
        int p = i + j;
        bool asc = ((i & k) == 0);
        unsigned long long A = sk[i], B = sk[p];
        if ((A > B) == asc) { sk[i] = B; sk[p] = A; }
      }
    }
    __syncthreads();
    {
      unsigned long long x[8];
      const int baseI = tid * 8;
      const bool asc = ((baseI & k) == 0);   // k>=16: uniform across the 8
      #pragma unroll
      for (int v = 0; v < 8; ++v) x[v] = sk[baseI + v];
      #pragma unroll
      for (int j = 4; j > 0; j >>= 1) {
        #pragma unroll
        for (int v = 0; v < 8; ++v) {
          int p = v ^ j;
          if (p > v) {
            unsigned long long A = x[v], B = x[p];
            if ((A > B) == asc) { x[v] = B; x[p] = A; }
          }
        }
      }
      #pragma unroll
      for (int v = 0; v < 8; ++v) sk[baseI + v] = x[v];
    }
  }
  __syncthreads();
  uint16_t* ordG = (uint16_t*)(ws + WS_ORD) + (size_t)t * NSORT;
  for (int i = tid; i < NSORT; i += 256) ordG[i] = (uint16_t)((unsigned)sk[i]);
}

// ============ K2b: wave-cooperative Kruskal over sorted order ============
__global__ __launch_bounds__(256) void k2b_kruskal(char* __restrict__ ws) {
  __shared__ uint16_t par[NPIX];
  __shared__ uint16_t tot[NPIX];
  const int tid = threadIdx.x, t = blockIdx.x;
  const int win = (t >> 1) & 63, bat = t >> 7;
  const int pw = bat * 64 + win;
  uint32_t* MG = (uint32_t*)(ws + WS_M);
  if (((const uint32_t*)(ws + WS_SKIP))[win]) { if (tid == 0) MG[t] = 0u; return; }
  const uint16_t* labG = (const uint16_t*)(ws + WS_LAB) + (size_t)pw * NPIX;
  for (int p = tid; p < NPIX; p += 256) {
    par[p] = (uint16_t)p; tot[p] = labG[p] ? 1 : 0;
  }
  __syncthreads();
  // wave 0 only; first 1984 sorted slots are always real edges (padding sorts last).
  // All ballots/readlanes in uniform control flow (CDNA exec-mask rule).
  if (tid < 64) {
    const int lane = tid;
    const uint16_t* ordG = (const uint16_t*)(ws + WS_ORD) + (size_t)t * NSORT;
    uint32_t* recG = (uint32_t*)(ws + WS_REC)  + (size_t)t * NPIX;
    uint32_t* totG = (uint32_t*)(ws + WS_TOTP) + (size_t)t * NPIX;
    int mTotal = 0;
    for (int base = 0; base < NEDGE; base += 64) {       // 31 full batches
      unsigned e = (unsigned)ordG[base + lane];
      int a, b; edge_nodes((int)e, a, b);
      int xa = a, xb = b;
      for (;;) {
        int pa = par[xa], pb = par[xb];    // read-only dual walk
        if (pa == xa && pb == xb) break;
        xa = pa; xb = pb;
      }
      int ra = xa, rb = xb;
      unsigned sa = tot[ra], sb = tot[rb];
      bool cand = (ra != rb);
      unsigned long long cm = __ballot(cand);
      unsigned w0 = (unsigned)ra | ((unsigned)rb << 10) | (e << 20);
      unsigned w1 = sa | (sb << 11);

      int mb = 0;
      int mFrom = -1, mTo = -1; unsigned szTo = 0;
      while (cm) {
        int i = __ffsll((long long)cm) - 1;
        cm &= cm - 1;
        unsigned W0 = (unsigned)__builtin_amdgcn_readlane((int)w0, i);
        unsigned W1 = (unsigned)__builtin_amdgcn_readlane((int)w1, i);
        int rA = (int)(W0 & 1023u);
        int rB = (int)((W0 >> 10) & 1023u);
        unsigned eI = W0 >> 20;
        unsigned sA = W1 & 2047u;
        unsigned sB = W1 >> 11;
        {  // O(1) chase via always-current mTo invariant
          unsigned long long mm = __ballot(mFrom == rA);
          if (mm) rA = __builtin_amdgcn_readlane(mTo, __ffsll((long long)mm) - 1);
          mm = __ballot(mFrom == rB);
          if (mm) rB = __builtin_amdgcn_readlane(mTo, __ffsll((long long)mm) - 1);
        }
        if (rA == rB) continue;
        {  // current sizes: highest slot with mTo==r holds current size
          unsigned long long ma = __ballot(mTo == rA);
          if (ma) sA = (unsigned)__builtin_amdgcn_readlane((int)szTo, 63 - __clzll((long long)ma));
          unsigned long long mbm = __ballot(mTo == rB);
          if (mbm) sB = (unsigned)__builtin_amdgcn_readlane((int)szTo, 63 - __clzll((long long)mbm));
        }
        if (lane == mb) { mFrom = rB; mTo = rA; szTo = sA + sB; }
        if (mTo == rB) mTo = rA;            // maintain invariant
        ++mb;
        if (lane == 0) {
          par[rB] = (uint16_t)rA;           // reference orientation
          tot[rA] = (uint16_t)(sA + sB);    // single writer: plain store
          if (sB > 0) {
            recG[mTotal] = eI | ((unsigned)rA << 11) | ((unsigned)rB << 21);
            totG[mTotal] = sA * sB;
          }
        }
        if (sB > 0) ++mTotal;               // uniform
      }
      // batched pointer-jump compression (1 write/node, conflict-free)
      if (mb && (base + 64 < NEDGE)) {
        for (int pass = 0; pass < 2; ++pass) {
          uint16_t vv[16];
          #pragma unroll
          for (int j = 0; j < 16; ++j) vv[j] = par[j * 64 + lane];
          #pragma unroll
          for (int j = 0; j < 16; ++j) vv[j] = par[vv[j]];
          #pragma unroll
          for (int j = 0; j < 16; ++j) par[j * 64 + lane] = vv[j];
        }
      }
    }
    if (lane == 0) MG[t] = (uint32_t)mTotal;
  }
}

// ============ K3: per-label replay (pipelined run-cache) + loss epilogue ============
__global__ __launch_bounds__(256) void k3_replay(char* __restrict__ ws) {
  __shared__ union {
    uint16_t cnt[CHUNK][CNTW];   // 32832 B
    double   red[256];
  } u;
  __shared__ uint32_t recW[NPIX];
  __shared__ uint32_t totp[NPIX];
  __shared__ uint32_t same[NPIX];
  __shared__ float    Pw[NPIX];
  __shared__ uint16_t lab[NPIX];
  __shared__ uint16_t labD[NPIX];
  __shared__ unsigned Ssum;
  const int tid = threadIdx.x, t = blockIdx.x;
  const int sign = t & 1, win = (t >> 1) & 63, bat = t >> 7;
  const int pw = bat * 64 + win;
  double* partG = (double*)(ws + WS_PART);
  if (((const uint32_t*)(ws + WS_SKIP))[win]) { if (tid == 0) partG[t] = 0.0; return; }
  const int M    = (int)((const uint32_t*)(ws + WS_M))[t];
  const int nlab = (int)((const uint32_t*)(ws + WS_NLAB))[pw];
  {
    const uint32_t* recG  = (const uint32_t*)(ws + WS_REC)  + (size_t)t * NPIX;
    const uint32_t* totG  = (const uint32_t*)(ws + WS_TOTP) + (size_t)t * NPIX;
    const float*    PwG   = (const float*)(ws + WS_PW)   + (size_t)pw * NPIX;
    const uint16_t* labG  = (const uint16_t*)(ws + WS_LAB)  + (size_t)pw * NPIX;
    const uint16_t* labDG = (const uint16_t*)(ws + WS_LABD) + (size_t)pw * NPIX;
    for (int m = tid; m < M; m += 256) { recW[m] = recG[m]; totp[m] = totG[m]; same[m] = 0u; }
    for (int p = tid; p < NPIX; p += 256) { Pw[p] = PwG[p]; lab[p] = labG[p]; labD[p] = labDG[p]; }
  }
  if (tid == 0) Ssum = 0u;
  __syncthreads();

  for (int chb = 0; chb < nlab; chb += CHUNK) {
    for (int i = tid; i < (CHUNK * CNTW) / 2; i += 256) ((uint32_t*)u.cnt)[i] = 0u;
    __syncthreads();
    for (int p = tid; p < NPIX; p += 256) {
      if (lab[p]) {
        int dl = (int)labD[lab[p] - 1] - 1 - chb;   // active id or <0
        if (dl >= 0 && dl < CHUNK) u.cnt[dl][p] = 1;
      }
    }
    __syncthreads();
    // serial replay, 16 label-lanes, 1-deep software pipeline.
    // LDS state is current except: cnt[lastRa] (register lastVal) and, for loads
    // issued before the previous iteration's flush, cnt[pfr] (register pfv).
    if (tid < CHUNK && M > 0) {
      int lastRa = -1; unsigned lastVal = 0;
      int pfr = -1; unsigned pfv = 0;
      unsigned w = recW[0];
      int ra = (int)((w >> 11) & 1023u), rb = (int)(w >> 21);
      unsigned caL = u.cnt[tid][ra], cbL = u.cnt[tid][rb];
      for (int m = 0; m < M; ++m) {
        int mn = (m + 1 < M) ? m + 1 : m;
        unsigned wN = recW[mn];                       // prefetch (pre-flush: stale set <= {lastRa, pfr})
        int raN = (int)((wN >> 11) & 1023u), rbN = (int)(wN >> 21);
        unsigned caN = u.cnt[tid][raN], cbN = u.cnt[tid][rbN];
        unsigned ca = (ra == lastRa) ? lastVal : ((ra == pfr) ? pfv : caL);
        unsigned cb = (rb == lastRa) ? lastVal : ((rb == pfr) ? pfv : cbL);
        int npfr = -1; unsigned npfv = 0;
        if (ra != lastRa) {
          if (lastRa >= 0) { u.cnt[tid][lastRa] = (uint16_t)lastVal; npfr = lastRa; npfv = lastVal; }
          lastRa = ra; lastVal = ca;
        }
        if (cb) {
          if (lastVal) atomicAdd(&same[m], lastVal * cb);
          lastVal += cb;
        }
        pfr = npfr; pfv = npfv;
        ra = raN; rb = rbN; caL = caN; cbL = cbN;
      }
    }
    __syncthreads();
  }

  unsigned mys = 0u;
  for (int m = tid; m < M; m += 256)
    mys += sign ? same[m] : (totp[m] - same[m]);
  atomicAdd(&Ssum, mys);
  __syncthreads();
  const unsigned S = Ssum;

  double part = 0.0;
  if (S > 0u) {
    for (int m = tid; m < M; m += 256) {
      unsigned np = sign ? same[m] : (totp[m] - same[m]);
      if (np == 0u) continue;
      int e = (int)(recW[m] & 2047u);
      int a, b; edge_nodes(e, a, b);
      int cls = (lab[a] ? 0 : 1) + (lab[b] ? 0 : 1);
      bool keep = sign ? (cls != 0)    // ewp[gt<20]=0 -> keep cls 1,2
                       : (cls == 0);   // ewn[gt>=10]=0 -> keep cls 0
      if (!keep) continue;
      double fa, fb;
      if (sign) {
        double da = 20.0 - (double)Pw[a], db = 20.0 - (double)Pw[b];
        fa = da * da; fb = db * db;
      } else {
        fa = (double)Pw[a] * (double)Pw[a];
        fb = (double)Pw[b] * (double)Pw[b];
      }
      part += (double)np * (fa + fb);
    }
  }
  u.red[tid] = part;
  __syncthreads();
  for (int st = 128; st > 0; st >>= 1) {
    if (tid < st) u.red[tid] += u.red[tid + st];
    __syncthreads();
  }
  if (tid == 0) partG[t] = (S > 0u) ? (u.red[0] / (double)S) : 0.0;
}

__global__ __launch_bounds__(256) void final_reduce(
    const double* __restrict__ part, float* __restrict__ out)
{
  __shared__ double r[256];
  int tdx = threadIdx.x;
  r[tdx] = part[tdx];
  __syncthreads();
  for (int st = 128; st > 0; st >>= 1) {
    if (tdx < st) r[tdx] += r[tdx + st];
    __syncthreads();
  }
  if (tdx == 0) out[0] = (float)r[0];
}

extern "C" void kernel_launch(void* const* d_in, const int* in_sizes, int n_in,
                              void* d_out, int out_size, void* d_ws, size_t ws_size,
                              hipStream_t stream) {
  const float* y_true = (const float*)d_in[0];
  const float* y_pred = (const float*)d_in[1];
  char* ws = (char*)d_ws;
  k1_prep<<<128, 256, 0, stream>>>(y_true, y_pred, ws);
  k2a_sort<<<256, 256, 0, stream>>>(ws);
  k2b_kruskal<<<256, 256, 0, stream>>>(ws);
  k3_replay<<<256, 256, 0, stream>>>(ws);
  final_reduce<<<1, 256, 0, stream>>>((const double*)(ws + WS_PART), (float*)d_out);
}